// Round 19
// baseline (296.949 us; speedup 1.0000x reference)
//
#include <hip/hip_runtime.h>

#define GROUPS 32
#define EPS 1e-5f

typedef unsigned short u16;
typedef __bf16 bf16x8 __attribute__((ext_vector_type(8)));
typedef float f32x4 __attribute__((ext_vector_type(4)));

__device__ __forceinline__ u16 f2bf(float f) {
  unsigned x = __builtin_bit_cast(unsigned, f);
  x += 0x7FFFu + ((x >> 16) & 1u);
  return (u16)(x >> 16);
}
__device__ __forceinline__ float bf2f(u16 u) {
  unsigned x = ((unsigned)u) << 16;
  return __builtin_bit_cast(float, x);
}

__device__ __forceinline__ void gload_lds16(const void* g, void* l) {
  __builtin_amdgcn_global_load_lds(
      (const __attribute__((address_space(1))) void*)g,
      (__attribute__((address_space(3))) void*)l, 16, 0, 0);
}

// ======== prep: groupnorm + weight cvt + bias concat + lsum/bar zero ======
__global__ __launch_bounds__(256) void prep_kernel(
    const float* __restrict__ x, const float* __restrict__ gamma,
    const float* __restrict__ beta, u16* __restrict__ HT,
    const float* __restrict__ wq, const float* __restrict__ wk,
    const float* __restrict__ wv, const float* __restrict__ wo,
    const float* __restrict__ bq, const float* __restrict__ bk,
    u16* __restrict__ Wqk, u16* __restrict__ Wv, u16* __restrict__ Wo,
    float* __restrict__ bqk, float* __restrict__ lsum,
    unsigned* __restrict__ bar, int C, int S, int CC, int NG) {
  __shared__ float xs[16 * 1024];
  __shared__ float rs[4], rss[4];
  int b = blockIdx.x;
  int tid = threadIdx.x;

  if (b >= NG) {  // ---- cvt / bias / zero branch
    int cb = b - NG;
    if (cb < 1024) {          // weight convert
      int w = cb >> 8, blk = cb & 255;
      const float* src;
      u16* dst;
      switch (w) {
        case 0: src = wq; dst = Wqk; break;
        case 1: src = wk; dst = Wqk + CC; break;
        case 2: src = wv; dst = Wv; break;
        default: src = wo; dst = Wo; break;
      }
      int i = (blk * 256 + tid) * 4;
      float4 v = *(const float4*)&src[i];
      ushort4 o;
      o.x = f2bf(v.x); o.y = f2bf(v.y); o.z = f2bf(v.z); o.w = f2bf(v.w);
      *(ushort4*)&dst[i] = o;
    } else if (cb < 1028) {   // bias concat
      int j = (cb - 1024) * 256 + tid;
      if (j < C) bqk[j] = bq[j];
      else if (j < 2 * C) bqk[j] = bk[j - C];
    } else if (cb < 1044) {   // zero lsum
      int i = (cb - 1028) * 1024 + tid * 4;
      *(float4*)&lsum[i] = make_float4(0.f, 0.f, 0.f, 0.f);
    } else {                  // zero grid barrier
      if (tid == 0) *bar = 0u;
    }
    return;
  }

  // ---- groupnorm branch
  const int cpg = C / GROUPS;  // 16
  int n = b / GROUPS;
  int g = b % GROUPS;
  const float* xb = x + ((size_t)n * C + (size_t)g * cpg) * S;
  int cnt = cpg * S;
  float s = 0.f, ss = 0.f;
  for (int i = tid * 4; i < cnt; i += 256 * 4) {
    float4 v = *(const float4*)&xb[i];
    *(float4*)&xs[i] = v;
    s += v.x + v.y + v.z + v.w;
    ss += v.x * v.x + v.y * v.y + v.z * v.z + v.w * v.w;
  }
  for (int o = 32; o > 0; o >>= 1) {
    s += __shfl_xor(s, o);
    ss += __shfl_xor(ss, o);
  }
  int wave = tid >> 6, lane = tid & 63;
  if (lane == 0) { rs[wave] = s; rss[wave] = ss; }
  __syncthreads();
  float S1 = rs[0] + rs[1] + rs[2] + rs[3];
  float S2 = rss[0] + rss[1] + rss[2] + rss[3];
  float mean = S1 / (float)cnt;
  float var = S2 / (float)cnt - mean * mean;
  float rstd = rsqrtf(var + EPS);
  float gm[16], bt[16];
#pragma unroll
  for (int c = 0; c < 16; ++c) {
    float gmv = gamma[g * cpg + c] * rstd;
    gm[c] = gmv;
    bt[c] = beta[g * cpg + c] - mean * gmv;
  }
  for (int i = 0; i < S; i += 256) {
    int sp = i + tid;
    u16 outv[16];
#pragma unroll
    for (int c = 0; c < 16; ++c) {
      float h = xs[c * 1024 + sp] * gm[c] + bt[c];
      outv[c] = f2bf(h);
    }
    u16* dst = HT + ((size_t)n * S + sp) * C + g * cpg;
    *(int4*)dst = *(int4*)&outv[0];
    *(int4*)&dst[8] = *(int4*)&outv[8];
  }
}

// =================== 256x128x32 2-phase GEMM body (8 waves) ================
// Round-8/16 proven structure, verbatim. Batch->XCD z-map. 0-conflict LDS
// line layout. epi_mode: 0 normal, 1 expP+atomic lsum, 2 colscale.
__device__ __forceinline__ void gemm_body(
    int bid, int nblk,
    const u16* __restrict__ A, long lda, long strideA,
    const u16* __restrict__ B, long ldb, long strideB,
    void* __restrict__ Out, long ldo, long strideO, int out_fp32,
    const float* __restrict__ bias, int bias_mode,
    float scale, const float* __restrict__ residual, int K,
    int nbx, int nby, u16* lds, int epi_mode, float* epi_ptr) {
  u16* As0 = lds;
  u16* Bs0 = lds + 8192;
  u16* As1 = lds + 12288;
  u16* Bs1 = lds + 20480;

  int tid = threadIdx.x;
  int wave = tid >> 6, lane = tid & 63;
  int wr = wave >> 1, wc = wave & 1;
  int l15 = lane & 15, l4 = lane >> 4;

  int tilesPB = nbx * nby;
  int nz = nblk / tilesPB;
  int z, rem;
  if ((nz & 7) == 0) {
    int e = bid & 7, j = bid >> 3;
    z = e + 8 * (j / tilesPB);
    rem = j % tilesPB;
  } else {
    int swz = ((nblk & 7) == 0) ? (bid & 7) * (nblk >> 3) + (bid >> 3) : bid;
    z = swz / tilesPB; rem = swz % tilesPB;
  }
  int bx = rem % nbx, by = rem / nbx;

  const u16* Ab = A + (long)z * strideA + (long)by * 256 * lda;
  const u16* Bb = B + (long)z * strideB + (long)bx * 128 * ldb;

  auto STAGE = [&](u16* Ad, u16* Bd, int kt) {
#pragma unroll
    for (int i = 0; i < 2; ++i) {
      int c = i * 512 + tid;
      int l = c >> 3, p = c & 7;
      int q = p ^ (l & 7);
      int row = 2 * l + (q >> 2);
      long koff = (long)kt * 32 + (q & 3) * 8;
      int lbase = (i * 512 + wave * 64) * 8;
      gload_lds16(Ab + (long)row * lda + koff, Ad + lbase);
    }
    {
      int c = tid;
      int l = c >> 3, p = c & 7;
      int q = p ^ (l & 7);
      int row = 2 * l + (q >> 2);
      long koff = (long)kt * 32 + (q & 3) * 8;
      int lbase = (wave * 64) * 8;
      gload_lds16(Bb + (long)row * ldb + koff, Bd + lbase);
    }
  };

  f32x4 acc[4][4] = {};

  auto COMPUTE = [&](const u16* Asrc, const u16* Bsrc) {
    bf16x8 af[4], bfr[4];
#pragma unroll
    for (int m = 0; m < 4; ++m) {
      int R = wr * 64 + m * 16 + l15;
      int line = R >> 1;
      int p = ((R & 1) * 4 + l4) ^ (line & 7);
      af[m] = *(const bf16x8*)&Asrc[line * 64 + p * 8];
    }
#pragma unroll
    for (int n = 0; n < 4; ++n) {
      int R = wc * 64 + n * 16 + l15;
      int line = R >> 1;
      int p = ((R & 1) * 4 + l4) ^ (line & 7);
      bfr[n] = *(const bf16x8*)&Bsrc[line * 64 + p * 8];
    }
#pragma unroll
    for (int m = 0; m < 4; ++m)
#pragma unroll
      for (int n = 0; n < 4; ++n)
        acc[m][n] = __builtin_amdgcn_mfma_f32_16x16x32_bf16(
            af[m], bfr[n], acc[m][n], 0, 0, 0);
  };

  int NT = K >> 5;
  u16 *Ar = As0, *Br = Bs0, *Aw = As1, *Bw = Bs1;

  STAGE(Ar, Br, 0);
  asm volatile("s_waitcnt vmcnt(0)" ::: "memory");
  __builtin_amdgcn_sched_barrier(0);
  __builtin_amdgcn_s_barrier();
  __builtin_amdgcn_sched_barrier(0);

  for (int t = 0; t < NT - 1; ++t) {
    STAGE(Aw, Bw, t + 1);
    COMPUTE(Ar, Br);
    asm volatile("s_waitcnt vmcnt(0)" ::: "memory");
    __builtin_amdgcn_sched_barrier(0);
    __builtin_amdgcn_s_barrier();
    __builtin_amdgcn_sched_barrier(0);
    u16* tp;
    tp = Ar; Ar = Aw; Aw = tp;
    tp = Br; Br = Bw; Bw = tp;
  }
  COMPUTE(Ar, Br);

  long orow0 = (long)by * 256 + wr * 64;
  long ocol0 = (long)bx * 128 + wc * 64;
  long rows_pb = 256L * nby;
  long cols_pb = 128L * nbx;

  float inv4[4];
  if (epi_mode == 2) {
#pragma unroll
    for (int n = 0; n < 4; ++n)
      inv4[n] = 1.f / epi_ptr[z * cols_pb + ocol0 + n * 16 + l15];
  }
  float rowpart[4][4];
  if (epi_mode == 1) {
#pragma unroll
    for (int m = 0; m < 4; ++m)
#pragma unroll
      for (int r = 0; r < 4; ++r) rowpart[m][r] = 0.f;
  }

#pragma unroll
  for (int m = 0; m < 4; ++m) {
#pragma unroll
    for (int n = 0; n < 4; ++n) {
#pragma unroll
      for (int r = 0; r < 4; ++r) {
        long row = orow0 + m * 16 + l4 * 4 + r;
        long col = ocol0 + n * 16 + l15;
        long off = (long)z * strideO + row * ldo + col;
        float v = acc[m][n][r] * scale;
        if (epi_mode == 1) {
          u16 e = f2bf(__expf(v));
          ((u16*)Out)[off] = e;
          rowpart[m][r] += bf2f(e);
        } else {
          if (epi_mode == 2) v *= inv4[n];
          if (bias_mode == 1) v += bias[row];
          else if (bias_mode == 2) v += bias[col];
          if (residual) v += residual[off];
          if (out_fp32) ((float*)Out)[off] = v;
          else ((u16*)Out)[off] = f2bf(v);
        }
      }
    }
  }

  if (epi_mode == 1) {
#pragma unroll
    for (int m = 0; m < 4; ++m)
#pragma unroll
      for (int r = 0; r < 4; ++r) {
        float t = rowpart[m][r];
        t += __shfl_xor(t, 1);
        t += __shfl_xor(t, 2);
        t += __shfl_xor(t, 4);
        t += __shfl_xor(t, 8);
        if (l15 == 0) {
          long row = orow0 + m * 16 + l4 * 4 + r;
          atomicAdd(&epi_ptr[z * rows_pb + row], t);
        }
      }
  }
}

// ---------------- software grid barrier (all 512 blocks resident) ----------
__device__ __forceinline__ void grid_sync(unsigned* bar, unsigned target) {
  __syncthreads();
  if (threadIdx.x == 0) {
    __threadfence();                       // release prior global writes
    atomicAdd(bar, 1u);
    while (__hip_atomic_load(bar, __ATOMIC_RELAXED,
                             __HIP_MEMORY_SCOPE_AGENT) < target)
      __builtin_amdgcn_s_sleep(8);
    __threadfence();                       // acquire
  }
  __syncthreads();
}

// ============ mega-kernel: proj + expP + PV + out in ONE dispatch ==========
// 512 blocks x 512 threads, 48 KB LDS -> exactly 2 blocks/CU (all resident).
// Phase A: QK-proj (512 jobs) + V-proj (256 jobs, blocks<256)
// Phase B: expP + lsum (512 jobs)   Phase C: PV (256)   Phase D: out (256)
__global__ __launch_bounds__(512, 4) void mega_kernel(
    const u16* __restrict__ HT, const u16* __restrict__ Wqk,
    const u16* __restrict__ Wv, const u16* __restrict__ Wo,
    u16* __restrict__ QKT, u16* __restrict__ Vb, u16* __restrict__ P,
    u16* __restrict__ H2T, const float* __restrict__ bqk,
    const float* __restrict__ bv, const float* __restrict__ bo,
    const float* __restrict__ x, float* __restrict__ Out,
    float* __restrict__ lsum, unsigned* __restrict__ bar,
    float scl, int C, int S) {
  __shared__ u16 lds[24576];
  long SC = (long)S * C, S2C = (long)S * 2 * C, SS = (long)S * S;
  int b = blockIdx.x;
  unsigned G = gridDim.x;  // 512

  // ---- Phase A: QKV projections
  gemm_body(b, 512, HT, C, SC, Wqk, C, 0, QKT, 2 * C, S2C, 0, bqk, 2, 1.f,
            nullptr, C, 2 * C / 128, S / 256, lds, 0, nullptr);
  if (b < 256) {
    __syncthreads();  // LDS WAR between consecutive bodies
    gemm_body(b, 256, Wv, C, 0, HT, C, SC, Vb, S, SC, 0, bv, 1, 1.f,
              nullptr, C, S / 128, C / 256, lds, 0, nullptr);
  }
  grid_sync(bar, G);

  // ---- Phase B: expP + row sums
  gemm_body(b, 512, QKT, 2 * C, S2C, QKT + C, 2 * C, S2C, P, S, SS, 0,
            nullptr, 0, scl, nullptr, C, S / 128, S / 256, lds, 1, lsum);
  grid_sync(bar, 2 * G);

  // ---- Phase C: PV
  if (b < 256)
    gemm_body(b, 256, P, S, SS, Vb, S, SC, H2T, C, SC, 0, nullptr, 0, 1.f,
              nullptr, S, C / 128, S / 256, lds, 0, nullptr);
  grid_sync(bar, 3 * G);

  // ---- Phase D: out-projection (fp32 + residual + 1/lsum)
  if (b < 256)
    gemm_body(b, 256, Wo, C, 0, H2T, C, SC, Out, S, SC, 1, bo, 1, 1.f,
              x, C, S / 128, C / 256, lds, 2, lsum);
}

extern "C" void kernel_launch(void* const* d_in, const int* in_sizes, int n_in,
                              void* d_out, int out_size, void* d_ws, size_t ws_size,
                              hipStream_t stream) {
  const float* x = (const float*)d_in[0];
  const float* gamma = (const float*)d_in[1];
  const float* beta = (const float*)d_in[2];
  const float* wq = (const float*)d_in[3];
  const float* bq = (const float*)d_in[4];
  const float* wk = (const float*)d_in[5];
  const float* bk = (const float*)d_in[6];
  const float* wv = (const float*)d_in[7];
  const float* bv = (const float*)d_in[8];
  const float* wo = (const float*)d_in[9];
  const float* bo = (const float*)d_in[10];

  const int C = 512, S = 1024;
  const int N = in_sizes[0] / (C * S);  // 16
  const int CC = C * C;

  char* ws = (char*)d_ws;
  const size_t MB = 1024 * 1024;
  u16* HT = (u16*)(ws + 0 * MB);      // [N,S,C]   0..16 MB
  u16* QKT = (u16*)(ws + 16 * MB);    // [N,S,2C]  16..48 MB
  u16* Vb = (u16*)(ws + 48 * MB);     // [N,C,S]   48..64 MB
  u16* P = (u16*)(ws + 64 * MB);      // [N,S,S]   64..96 MB
  u16* Wqk = (u16*)(ws + 96 * MB);    // [2C,C]
  u16* Wv = Wqk + 2 * CC;
  u16* Wo = Wv + CC;
  float* bqk = (float*)(Wo + CC);     // [2C]
  float* lsum = bqk + 2 * C;          // [N*S]
  unsigned* bar = (unsigned*)(lsum + (size_t)N * S);
  u16* H2T = HT;                      // overlay: HT dead after proj phase

  const int NG = N * GROUPS;          // 512

  prep_kernel<<<dim3(NG + 1024 + 4 + 16 + 1), 256, 0, stream>>>(
      x, gamma, beta, HT, wq, wk, wv, wo, bq, bk, Wqk, Wv, Wo, bqk, lsum,
      bar, C, S, CC, NG);

  const float scl = 1.0f / sqrtf((float)C);

  mega_kernel<<<dim3(512), 512, 0, stream>>>(
      HT, Wqk, Wv, Wo, QKT, Vb, P, H2T, bqk, bv, bo, x, (float*)d_out,
      lsum, bar, scl, C, S);
}

// Round 20
// 162.352 us; speedup vs baseline: 1.8290x; 1.8290x over previous
//
#include <hip/hip_runtime.h>

#define GROUPS 32
#define EPS 1e-5f

typedef unsigned short u16;
typedef __bf16 bf16x8 __attribute__((ext_vector_type(8)));
typedef float f32x4 __attribute__((ext_vector_type(4)));

__device__ __forceinline__ u16 f2bf(float f) {
  unsigned x = __builtin_bit_cast(unsigned, f);
  x += 0x7FFFu + ((x >> 16) & 1u);
  return (u16)(x >> 16);
}
__device__ __forceinline__ float bf2f(u16 u) {
  unsigned x = ((unsigned)u) << 16;
  return __builtin_bit_cast(float, x);
}

__device__ __forceinline__ void gload_lds16(const void* g, void* l) {
  __builtin_amdgcn_global_load_lds(
      (const __attribute__((address_space(1))) void*)g,
      (__attribute__((address_space(3))) void*)l, 16, 0, 0);
}

// ======== prep: groupnorm + weight cvt + bias concat + lsum zero ==========
// blocks [0,512): groupnorm;  [512,1536): weight fp32->bf16 (4 x 256);
// [1536,1540): bias concat;   [1540,1556): zero lsum (N*S floats).
__global__ __launch_bounds__(256) void prep_kernel(
    const float* __restrict__ x, const float* __restrict__ gamma,
    const float* __restrict__ beta, u16* __restrict__ HT,
    const float* __restrict__ wq, const float* __restrict__ wk,
    const float* __restrict__ wv, const float* __restrict__ wo,
    const float* __restrict__ bq, const float* __restrict__ bk,
    u16* __restrict__ Wqk, u16* __restrict__ Wv, u16* __restrict__ Wo,
    float* __restrict__ bqk, float* __restrict__ lsum,
    int C, int S, int CC, int NG) {
  __shared__ float xs[16 * 1024];
  __shared__ float rs[4], rss[4];
  int b = blockIdx.x;
  int tid = threadIdx.x;

  if (b >= NG) {  // ---- cvt / bias / zero branch
    int cb = b - NG;
    if (cb < 1024) {          // weight convert: weight w, block blk
      int w = cb >> 8, blk = cb & 255;
      const float* src;
      u16* dst;
      switch (w) {
        case 0: src = wq; dst = Wqk; break;
        case 1: src = wk; dst = Wqk + CC; break;
        case 2: src = wv; dst = Wv; break;
        default: src = wo; dst = Wo; break;
      }
      int i = (blk * 256 + tid) * 4;
      float4 v = *(const float4*)&src[i];
      ushort4 o;
      o.x = f2bf(v.x); o.y = f2bf(v.y); o.z = f2bf(v.z); o.w = f2bf(v.w);
      *(ushort4*)&dst[i] = o;
    } else if (cb < 1028) {   // bias concat
      int j = (cb - 1024) * 256 + tid;
      if (j < C) bqk[j] = bq[j];
      else if (j < 2 * C) bqk[j] = bk[j - C];
    } else {                  // zero lsum
      int i = (cb - 1028) * 1024 + tid * 4;
      *(float4*)&lsum[i] = make_float4(0.f, 0.f, 0.f, 0.f);
    }
    return;
  }

  // ---- groupnorm branch
  const int cpg = C / GROUPS;  // 16
  int n = b / GROUPS;
  int g = b % GROUPS;
  const float* xb = x + ((size_t)n * C + (size_t)g * cpg) * S;
  int cnt = cpg * S;
  float s = 0.f, ss = 0.f;
  for (int i = tid * 4; i < cnt; i += 256 * 4) {
    float4 v = *(const float4*)&xb[i];
    *(float4*)&xs[i] = v;
    s += v.x + v.y + v.z + v.w;
    ss += v.x * v.x + v.y * v.y + v.z * v.z + v.w * v.w;
  }
  for (int o = 32; o > 0; o >>= 1) {
    s += __shfl_xor(s, o);
    ss += __shfl_xor(ss, o);
  }
  int wave = tid >> 6, lane = tid & 63;
  if (lane == 0) { rs[wave] = s; rss[wave] = ss; }
  __syncthreads();
  float S1 = rs[0] + rs[1] + rs[2] + rs[3];
  float S2 = rss[0] + rss[1] + rss[2] + rss[3];
  float mean = S1 / (float)cnt;
  float var = S2 / (float)cnt - mean * mean;
  float rstd = rsqrtf(var + EPS);
  float gm[16], bt[16];
#pragma unroll
  for (int c = 0; c < 16; ++c) {
    float gmv = gamma[g * cpg + c] * rstd;
    gm[c] = gmv;
    bt[c] = beta[g * cpg + c] - mean * gmv;
  }
  for (int i = 0; i < S; i += 256) {
    int sp = i + tid;
    u16 outv[16];
#pragma unroll
    for (int c = 0; c < 16; ++c) {
      float h = xs[c * 1024 + sp] * gm[c] + bt[c];
      outv[c] = f2bf(h);
    }
    u16* dst = HT + ((size_t)n * S + sp) * C + g * cpg;
    *(int4*)dst = *(int4*)&outv[0];
    *(int4*)&dst[8] = *(int4*)&outv[8];
  }
}

// =================== 256x128x32 2-phase GEMM body (8 waves) ================
// Round-8/15 best-measured structure. Batch->XCD z-map. 0-conflict LDS line
// layout: two rows interleave into one 64-elem line; granule (l,p) holds
// global (row=2l+(q>>2), kslot=q&3), q=p^(l&7).
// epi_mode: 0 = normal (scale/bias/residual/store)
//           1 = expP: write f2bf(exp(acc*scale)); atomic row-sum into epi_ptr
//           2 = colscale: v = acc*scale*(1/epi_ptr[col]) + bias + residual
__device__ __forceinline__ void gemm_body(
    int bid, int nblk,
    const u16* __restrict__ A, long lda, long strideA,
    const u16* __restrict__ B, long ldb, long strideB,
    void* __restrict__ Out, long ldo, long strideO, int out_fp32,
    const float* __restrict__ bias, int bias_mode,  // 0 none, 1 row, 2 col
    float scale, const float* __restrict__ residual, int K,
    int nbx, int nby, u16* lds, int epi_mode, float* epi_ptr) {
  u16* As0 = lds;
  u16* Bs0 = lds + 8192;
  u16* As1 = lds + 12288;
  u16* Bs1 = lds + 20480;

  int tid = threadIdx.x;
  int wave = tid >> 6, lane = tid & 63;
  int wr = wave >> 1, wc = wave & 1;   // 4 x 2 wave grid, 64x64 per wave
  int l15 = lane & 15, l4 = lane >> 4;

  int tilesPB = nbx * nby;
  int nz = nblk / tilesPB;
  int z, rem;
  if ((nz & 7) == 0) {        // batch->XCD mapping
    int e = bid & 7, j = bid >> 3;
    z = e + 8 * (j / tilesPB);
    rem = j % tilesPB;
  } else {
    int swz = ((nblk & 7) == 0) ? (bid & 7) * (nblk >> 3) + (bid >> 3) : bid;
    z = swz / tilesPB; rem = swz % tilesPB;
  }
  int bx = rem % nbx, by = rem / nbx;

  const u16* Ab = A + (long)z * strideA + (long)by * 256 * lda;
  const u16* Bb = B + (long)z * strideB + (long)bx * 128 * ldb;

  auto STAGE = [&](u16* Ad, u16* Bd, int kt) {
#pragma unroll
    for (int i = 0; i < 2; ++i) {       // A granules
      int c = i * 512 + tid;
      int l = c >> 3, p = c & 7;
      int q = p ^ (l & 7);
      int row = 2 * l + (q >> 2);
      long koff = (long)kt * 32 + (q & 3) * 8;
      int lbase = (i * 512 + wave * 64) * 8;
      gload_lds16(Ab + (long)row * lda + koff, Ad + lbase);
    }
    {                                   // B granules
      int c = tid;
      int l = c >> 3, p = c & 7;
      int q = p ^ (l & 7);
      int row = 2 * l + (q >> 2);
      long koff = (long)kt * 32 + (q & 3) * 8;
      int lbase = (wave * 64) * 8;
      gload_lds16(Bb + (long)row * ldb + koff, Bd + lbase);
    }
  };

  f32x4 acc[4][4] = {};

  auto COMPUTE = [&](const u16* Asrc, const u16* Bsrc) {
    bf16x8 af[4], bfr[4];
#pragma unroll
    for (int m = 0; m < 4; ++m) {
      int R = wr * 64 + m * 16 + l15;
      int line = R >> 1;
      int p = ((R & 1) * 4 + l4) ^ (line & 7);
      af[m] = *(const bf16x8*)&Asrc[line * 64 + p * 8];
    }
#pragma unroll
    for (int n = 0; n < 4; ++n) {
      int R = wc * 64 + n * 16 + l15;
      int line = R >> 1;
      int p = ((R & 1) * 4 + l4) ^ (line & 7);
      bfr[n] = *(const bf16x8*)&Bsrc[line * 64 + p * 8];
    }
#pragma unroll
    for (int m = 0; m < 4; ++m)
#pragma unroll
      for (int n = 0; n < 4; ++n)
        acc[m][n] = __builtin_amdgcn_mfma_f32_16x16x32_bf16(
            af[m], bfr[n], acc[m][n], 0, 0, 0);
  };

  int NT = K >> 5;
  u16 *Ar = As0, *Br = Bs0, *Aw = As1, *Bw = Bs1;

  STAGE(Ar, Br, 0);
  asm volatile("s_waitcnt vmcnt(0)" ::: "memory");
  __builtin_amdgcn_sched_barrier(0);
  __builtin_amdgcn_s_barrier();
  __builtin_amdgcn_sched_barrier(0);

  for (int t = 0; t < NT - 1; ++t) {
    STAGE(Aw, Bw, t + 1);       // issue next-tile loads first
    COMPUTE(Ar, Br);            // they fly under ds_read + MFMA
    asm volatile("s_waitcnt vmcnt(0)" ::: "memory");
    __builtin_amdgcn_sched_barrier(0);
    __builtin_amdgcn_s_barrier();
    __builtin_amdgcn_sched_barrier(0);
    u16* tp;
    tp = Ar; Ar = Aw; Aw = tp;
    tp = Br; Br = Bw; Bw = tp;
  }
  COMPUTE(Ar, Br);

  long orow0 = (long)by * 256 + wr * 64;
  long ocol0 = (long)bx * 128 + wc * 64;
  long rows_pb = 256L * nby;
  long cols_pb = 128L * nbx;

  float inv4[4];
  if (epi_mode == 2) {
#pragma unroll
    for (int n = 0; n < 4; ++n)
      inv4[n] = 1.f / epi_ptr[z * cols_pb + ocol0 + n * 16 + l15];
  }
  float rowpart[4][4];
  if (epi_mode == 1) {
#pragma unroll
    for (int m = 0; m < 4; ++m)
#pragma unroll
      for (int r = 0; r < 4; ++r) rowpart[m][r] = 0.f;
  }

#pragma unroll
  for (int m = 0; m < 4; ++m) {
#pragma unroll
    for (int n = 0; n < 4; ++n) {
#pragma unroll
      for (int r = 0; r < 4; ++r) {
        long row = orow0 + m * 16 + l4 * 4 + r;
        long col = ocol0 + n * 16 + l15;
        long off = (long)z * strideO + row * ldo + col;
        float v = acc[m][n][r] * scale;
        if (epi_mode == 1) {
          u16 e = f2bf(__expf(v));
          ((u16*)Out)[off] = e;
          rowpart[m][r] += bf2f(e);
        } else {
          if (epi_mode == 2) v *= inv4[n];
          if (bias_mode == 1) v += bias[row];
          else if (bias_mode == 2) v += bias[col];
          if (residual) v += residual[off];
          if (out_fp32) ((float*)Out)[off] = v;
          else ((u16*)Out)[off] = f2bf(v);
        }
      }
    }
  }

  if (epi_mode == 1) {  // reduce across the 16 cols each lane-group covers
#pragma unroll
    for (int m = 0; m < 4; ++m)
#pragma unroll
      for (int r = 0; r < 4; ++r) {
        float t = rowpart[m][r];
        t += __shfl_xor(t, 1);
        t += __shfl_xor(t, 2);
        t += __shfl_xor(t, 4);
        t += __shfl_xor(t, 8);
        if (l15 == 0) {
          long row = orow0 + m * 16 + l4 * 4 + r;
          atomicAdd(&epi_ptr[z * rows_pb + row], t);
        }
      }
  }
}

__global__ __launch_bounds__(512, 4) void gemm256x128_kernel(
    const u16* __restrict__ A, long lda, long strideA,
    const u16* __restrict__ B, long ldb, long strideB,
    void* __restrict__ Out, long ldo, long strideO, int out_fp32,
    const float* __restrict__ bias, int bias_mode,
    float scale, const float* __restrict__ residual, int K, int nbx, int nby,
    int epi_mode, float* epi_ptr) {
  __shared__ u16 lds[24576];
  gemm_body(blockIdx.x, gridDim.x, A, lda, strideA, B, ldb, strideB,
            Out, ldo, strideO, out_fp32, bias, bias_mode, scale, residual,
            K, nbx, nby, lds, epi_mode, epi_ptr);
}

// -------- merged QK-proj + V-proj: 768 blocks, one dispatch ---------------
__global__ __launch_bounds__(512, 4) void projqkv_kernel(
    const u16* __restrict__ HT, const u16* __restrict__ Wqk,
    const u16* __restrict__ Wv, u16* __restrict__ QKT, u16* __restrict__ Vb,
    const float* __restrict__ bqk, const float* __restrict__ bv,
    int nQK, int C, int S) {
  __shared__ u16 lds[24576];
  long SC = (long)S * C, S2C = (long)S * 2 * C;
  if ((int)blockIdx.x < nQK) {
    gemm_body(blockIdx.x, nQK, HT, C, SC, Wqk, C, 0, QKT, 2 * C, S2C, 0,
              bqk, 2, 1.f, nullptr, C, 2 * C / 128, S / 256, lds, 0, nullptr);
  } else {
    gemm_body(blockIdx.x - nQK, gridDim.x - nQK, Wv, C, 0, HT, C, SC,
              Vb, S, SC, 0, bv, 1, 1.f, nullptr, C, S / 128, C / 256, lds,
              0, nullptr);
  }
}

extern "C" void kernel_launch(void* const* d_in, const int* in_sizes, int n_in,
                              void* d_out, int out_size, void* d_ws, size_t ws_size,
                              hipStream_t stream) {
  const float* x = (const float*)d_in[0];
  const float* gamma = (const float*)d_in[1];
  const float* beta = (const float*)d_in[2];
  const float* wq = (const float*)d_in[3];
  const float* bq = (const float*)d_in[4];
  const float* wk = (const float*)d_in[5];
  const float* bk = (const float*)d_in[6];
  const float* wv = (const float*)d_in[7];
  const float* bv = (const float*)d_in[8];
  const float* wo = (const float*)d_in[9];
  const float* bo = (const float*)d_in[10];

  const int C = 512, S = 1024;
  const int N = in_sizes[0] / (C * S);  // 16
  const long SC = (long)S * C;
  const long S2C = (long)S * 2 * C;
  const long SS = (long)S * S;
  const int CC = C * C;

  char* ws = (char*)d_ws;
  const size_t MB = 1024 * 1024;
  u16* HT = (u16*)(ws + 0 * MB);      // [N,S,C]   0..16 MB
  u16* QKT = (u16*)(ws + 16 * MB);    // [N,S,2C]  16..48 MB
  u16* Vb = (u16*)(ws + 48 * MB);     // [N,C,S]   48..64 MB
  u16* P = (u16*)(ws + 64 * MB);      // [N,S,S]   64..96 MB
  u16* Wqk = (u16*)(ws + 96 * MB);    // [2C,C]
  u16* Wv = Wqk + 2 * CC;
  u16* Wo = Wv + CC;
  float* bqk = (float*)(Wo + CC);     // [2C]
  float* lsum = bqk + 2 * C;          // [N*S] fp32 row sums of expP
  u16* H2T = HT;                      // overlay: HT dead after proj phase

  const int NG = N * GROUPS;          // 512

  // prep: groupnorm + weight cvt + bias concat + zero lsum, one dispatch
  prep_kernel<<<dim3(NG + 1024 + 4 + 16), 256, 0, stream>>>(
      x, gamma, beta, HT, wq, wk, wv, wo, bq, bk, Wqk, Wv, Wo, bqk, lsum,
      C, S, CC, NG);

  const float scl = 1.0f / sqrtf((float)C);
  const int nQK = (S / 256) * (2 * C / 128) * N;   // 512
  const int nV = (C / 256) * (S / 128) * N;        // 256

  // merged QK-proj + V-proj
  projqkv_kernel<<<dim3(nQK + nV), 512, 0, stream>>>(
      HT, Wqk, Wv, QKT, Vb, bqk, bv, nQK, C, S);
  // expP[s][t] = exp(scl * sum_c Q[s][c]*K[t][c]); lsum[s] += row sums
  gemm256x128_kernel<<<dim3((S / 256) * (S / 128) * N), 512, 0, stream>>>(
      QKT, 2 * C, S2C, QKT + C, 2 * C, S2C, P, S, SS, 0, nullptr, 0, scl,
      nullptr, C, S / 128, S / 256, 1, lsum);
  // H2Traw[s][c] = sum_t expP[s][t]*V[c][t]
  gemm256x128_kernel<<<dim3((S / 256) * (C / 128) * N), 512, 0, stream>>>(
      P, S, SS, Vb, S, SC, H2T, C, SC, 0, nullptr, 0, 1.f, nullptr, S,
      C / 128, S / 256, 0, nullptr);
  // out[c][s] = x + bo[c] + (sum_k Wo[c][k]*H2Traw[s][k]) / lsum[s]  (fp32)
  gemm256x128_kernel<<<dim3((C / 256) * (S / 128) * N), 512, 0, stream>>>(
      Wo, C, 0, H2T, C, SC, d_out, S, SC, 1, bo, 1, 1.f, x, C,
      S / 128, C / 256, 2, lsum);
}